// Round 15
// baseline (193.492 us; speedup 1.0000x reference)
//
#include <hip/hip_runtime.h>
#include <hip/hip_fp16.h>

#define T_DIM 2048
#define D_DIM 256
#define K_CODES 512
#define N_ROWS 131072
#define Q_ELEMS 33554432
#define FMQ_FIX 60000u   // 2.235e-4 * 2^28: f16-err margin (proven r6-8) + headroom

typedef __attribute__((ext_vector_type(8))) _Float16 f16x8;
typedef __attribute__((ext_vector_type(8))) short s16x8;
typedef __attribute__((ext_vector_type(4))) float f32x4;

// ws layout (bytes) -- proven footprint (rounds 9-14):
// [0, 2048)        norms (512 f32, numpy-pairwise-exact)
// [2048, 18432)    bsums (2048 f64, main loss partials)
// [36864, 40960)   bsums2 (512 f64, xpose sum(x^2) partials)
// [40960, 303104)  e16: f16(512*e), k-granule layout
// [303104, 67411968) x16: f16(x), k-granule per 64-row span
// out_idx[n] self-describing: plain I; pair I+1024*(I2+1); rescan I+1024*1023.

__device__ __forceinline__ float comb8(const float* r) {
  return ((r[0] + r[1]) + (r[2] + r[3])) + ((r[4] + r[5]) + (r[6] + r[7]));
}

// branchless top-3 insert on packed u32 keys (fixed-point score | code lo-9)
__device__ __forceinline__ void ins3(unsigned& m1, unsigned& m2, unsigned& m3, unsigned k) {
  unsigned t1 = max(m1, k); m1 = min(m1, k);
  unsigned t2 = max(m2, t1); m2 = min(m2, t1);
  m3 = min(m3, t2);
}

__device__ __forceinline__ void gl_lds16(const void* g, void* l) {
  __builtin_amdgcn_global_load_lds(
      (const __attribute__((address_space(1))) unsigned int*)g,
      (__attribute__((address_space(3))) unsigned int*)l, 16, 0, 0);
}

__global__ __launch_bounds__(256) void vq_prep(const float* __restrict__ e,
                                               float* __restrict__ norms,
                                               unsigned short* __restrict__ e16) {
  __shared__ float srow[D_DIM];
  int k = blockIdx.x, t = threadIdx.x;
  float v = e[k * D_DIM + t];
  srow[t] = v;
  e16[(k >> 5) * 8192 + (t >> 3) * 256 + (k & 31) * 8 + (t & 7)] =
      __half_as_ushort(__float2half(512.0f * v));
  __syncthreads();
  if (t == 0) {
    float res[2];
    #pragma unroll
    for (int h = 0; h < 2; ++h) {
      float r[8];
      #pragma unroll
      for (int j = 0; j < 8; ++j) { float a = srow[h * 128 + j]; r[j] = __fmul_rn(a, a); }
      for (int i = 8; i < 128; i += 8)
        #pragma unroll
        for (int j = 0; j < 8; ++j) { float a = srow[h * 128 + i + j]; r[j] = __fadd_rn(r[j], __fmul_rn(a, a)); }
      res[h] = comb8(r);
    }
    norms[k] = __fadd_rn(res[0], res[1]);
  }
}

__global__ __launch_bounds__(512, 1) void vq_xpose(const float* __restrict__ x,
                                                   unsigned short* __restrict__ x16,
                                                   double* __restrict__ bsums2) {
  __shared__ unsigned short tlu[32 * 2048];
  __shared__ double dred[8];
  const int tx = threadIdx.x, blk = blockIdx.x;
  const int b = blk >> 3, t0 = (blk & 7) * 256;
  const int w = tx >> 6, lane = tx & 63;

  float xsq = 0.f;
  #pragma unroll
  for (int g8 = 0; g8 < 4; ++g8) {
    unsigned short pk[4][8];
    #pragma unroll
    for (int dj = 0; dj < 8; ++dj) {
      int d = w * 32 + g8 * 8 + dj;
      float4 v = *(const float4*)(x + (size_t)(b * 256 + d) * 2048 + t0 + lane * 4);
      xsq = fmaf(v.x, v.x, xsq); xsq = fmaf(v.y, v.y, xsq);
      xsq = fmaf(v.z, v.z, xsq); xsq = fmaf(v.w, v.w, xsq);
      pk[0][dj] = __half_as_ushort(__float2half(v.x));
      pk[1][dj] = __half_as_ushort(__float2half(v.y));
      pk[2][dj] = __half_as_ushort(__float2half(v.z));
      pk[3][dj] = __half_as_ushort(__float2half(v.w));
    }
    int kg = w * 4 + g8;
    #pragma unroll
    for (int j = 0; j < 4; ++j)
      *(s16x8*)&tlu[kg * 2048 + (lane * 4 + j) * 8] = *(s16x8*)&pk[j][0];
  }
  __syncthreads();
  const size_t obase = (size_t)(b * 2048 + t0) * 256;
  #pragma unroll 4
  for (int i = 0; i < 16; ++i) {
    int q = tx + i * 512;
    s16x8 vv = *(const s16x8*)&tlu[((q >> 6) & 31) * 2048 + ((q >> 11) * 64 + (q & 63)) * 8];
    *(s16x8*)(x16 + obase + (size_t)q * 8) = vv;
  }
  double dv = (double)xsq;
  #pragma unroll
  for (int o = 32; o > 0; o >>= 1) dv += __shfl_down(dv, o, 64);
  if (lane == 0) dred[w] = dv;
  __syncthreads();
  if (tx == 0) {
    double s = 0.0;
    #pragma unroll
    for (int i = 0; i < 8; ++i) s += dred[i];
    bsums2[blk] = s;
  }
}

// T3 schedule (r11) + branchless fixed-point packed-key top-3 fold (r13/r14).
__global__ __launch_bounds__(256, 1) void vq_main(
    const float* __restrict__ norms, const unsigned short* __restrict__ e16,
    const unsigned short* __restrict__ x16, const float* __restrict__ e,
    float* __restrict__ out_q, float* __restrict__ out_idx,
    double* __restrict__ bsums) {
  __shared__ unsigned short Bu[2][8192];      // 32 KB: B dbuf; also A staging
  __shared__ float nlds[K_CODES];             // (norms[k]+2) * 2^28
  __shared__ unsigned wredk[2][3][64];
  __shared__ float rmin[64];
  __shared__ int   widx[64];
  __shared__ double dred[4];

  const int tx = threadIdx.x, blk = blockIdx.x;   // 2048 blocks x 64 rows
  const int lane = tx & 63, w = tx >> 6;
  const int wm = w & 1, wn = w >> 1;
  const int c = lane & 15, g = lane >> 4;

  nlds[tx] = (norms[tx] + 2.0f) * 268435456.0f;
  nlds[tx + 256] = (norms[tx + 256] + 2.0f) * 268435456.0f;

  #pragma unroll
  for (int i = 0; i < 8; ++i)
    gl_lds16(x16 + (size_t)blk * 16384 + i * 2048 + tx * 8, &Bu[0][0] + i * 2048 + w * 512);
  __syncthreads();
  f16x8 af2[2][8];
  #pragma unroll
  for (int mi = 0; mi < 2; ++mi)
    #pragma unroll
    for (int ch = 0; ch < 8; ++ch)
      af2[mi][ch] = *(const f16x8*)(&Bu[0][0] + (ch * 4 + g) * 512 + (wm * 32 + mi * 16 + c) * 8);
  __syncthreads();
  #pragma unroll
  for (int i = 0; i < 4; ++i)
    gl_lds16(e16 + i * 2048 + tx * 8, &Bu[0][i * 2048 + w * 512]);
  __syncthreads();

  unsigned mk1[8], mk2[8], mk3[8];
  #pragma unroll
  for (int si = 0; si < 8; ++si) { mk1[si] = 0xFFFFFFFFu; mk2[si] = 0xFFFFFFFFu; mk3[si] = 0xFFFFFFFFu; }

  for (int it = 0; it < 16; ++it) {
    if (it < 15) {
      #pragma unroll
      for (int i = 0; i < 4; ++i)
        gl_lds16(e16 + (size_t)(it + 1) * 8192 + i * 2048 + tx * 8,
                 &Bu[(it + 1) & 1][i * 2048 + w * 512]);
    }
    const unsigned short* bb = &Bu[it & 1][0];
    f32x4 acc[2];
    acc[0] = (f32x4){0.f, 0.f, 0.f, 0.f};
    acc[1] = (f32x4){0.f, 0.f, 0.f, 0.f};
    #pragma unroll
    for (int ch = 0; ch < 8; ++ch) {
      f16x8 bf = *(const f16x8*)&bb[(ch * 4 + g) * 256 + (wn * 16 + c) * 8];
      acc[0] = __builtin_amdgcn_mfma_f32_16x16x32_f16(af2[0][ch], bf, acc[0], 0, 0, 0);
      acc[1] = __builtin_amdgcn_mfma_f32_16x16x32_f16(af2[1][ch], bf, acc[1], 0, 0, 0);
    }
    unsigned code = (unsigned)(it * 32 + wn * 16 + c);
    float nrmS = nlds[code];
    #pragma unroll
    for (int mi = 0; mi < 2; ++mi)
      #pragma unroll
      for (int q = 0; q < 4; ++q) {
        int si = mi * 4 + q;
        float svf = fmaf(-1048576.0f, acc[mi][q], nrmS);   // ((nrm+2)-2*dot/512)*2^28
        unsigned key = ((unsigned)svf & 0xFFFFFE00u) | code;
        ins3(mk1[si], mk2[si], mk3[si], key);
      }
    __syncthreads();
  }

  #pragma unroll
  for (int si = 0; si < 8; ++si) {
    unsigned a1 = mk1[si], a2 = mk2[si], a3 = mk3[si];
    #pragma unroll
    for (int off = 1; off < 16; off <<= 1) {
      unsigned b1 = (unsigned)__shfl_xor((int)a1, off, 64);
      unsigned b2 = (unsigned)__shfl_xor((int)a2, off, 64);
      unsigned b3 = (unsigned)__shfl_xor((int)a3, off, 64);
      ins3(a1, a2, a3, b1); ins3(a1, a2, a3, b2); ins3(a1, a2, a3, b3);
    }
    if (c == 0) {
      int row = wm * 32 + (si >> 2) * 16 + g * 4 + (si & 3);
      wredk[wn][0][row] = a1; wredk[wn][1][row] = a2; wredk[wn][2][row] = a3;
    }
  }
  __syncthreads();

  if (tx < 64) {
    unsigned a1 = wredk[0][0][tx], a2 = wredk[0][1][tx], a3 = wredk[0][2][tx];
    ins3(a1, a2, a3, wredk[1][0][tx]);
    ins3(a1, a2, a3, wredk[1][1][tx]);
    ins3(a1, a2, a3, wredk[1][2][tx]);
    int I = (int)(a1 & 511u), I2 = (int)(a2 & 511u);
    unsigned s1 = a1 & 0xFFFFFE00u, s2 = a2 & 0xFFFFFE00u, s3 = a3 & 0xFFFFFE00u;
    rmin[tx] = (float)s1 * 3.7252903e-9f - 2.0f;   // /2^28 - 2
    widx[tx] = I;
    bool rescan = (s3 - s1 <= FMQ_FIX);
    bool pairf  = (s2 - s1 <= FMQ_FIX) && !rescan;
    int enc = I;
    if (pairf)  enc = I + 1024 * (I2 + 1);
    if (rescan) enc = I + 1024 * 1023;
    out_idx[(size_t)blk * 64 + tx] = (float)enc;
  }
  __syncthreads();

  #pragma unroll 4
  for (int i = 0; i < 16; ++i) {
    int row = w * 16 + i;
    int k = widx[row];
    float4 ev = *(const float4*)(e + (size_t)k * D_DIM + lane * 4);
    *(float4*)(out_q + ((size_t)blk * 64 + row) * D_DIM + lane * 4) = ev;
  }

  double dv = (tx < 64) ? (double)rmin[tx] : 0.0;
  #pragma unroll
  for (int o = 32; o > 0; o >>= 1) dv += __shfl_down(dv, o, 64);
  if (lane == 0) dred[w] = dv;
  __syncthreads();
  if (tx == 0) bsums[blk] = (dred[0] + dred[1]) + (dred[2] + dred[3]);
}

// r15 epilogue: COALESCED x-tile staging. A flagged block stages its whole
// [256d x 64t] fp32 slab into LDS (wave w: d in [64w,64w+64), lane = t;
// 256B contiguous segments) -- replaces r14's per-row scattered gather
// (4B useful per 64B line -> 660 GB/s). All exact chains (numpy-replica,
// op-order identical to validated r6-14 forms) read LDS.
__global__ __launch_bounds__(256) void vq_epilogue(
    const float* __restrict__ x, const float* __restrict__ e,
    const float* __restrict__ norms,
    float* __restrict__ out_q, float* __restrict__ out_idx) {
  __shared__ float xs[64][257];     // 65.8 KB, +1 pad: 2-way banks on staging
  __shared__ float epair[4][2][256];
  __shared__ float xr16[4][16];
  const int tx = threadIdx.x, blk = blockIdx.x;
  const int lane = tx & 63, w = tx >> 6;

  int iv = (int)out_idx[(size_t)blk * 64 + lane];
  int f = iv >> 10;
  unsigned long long bm = __ballot(f != 0);   // identical across the 4 waves
  if (!bm) return;

  // coalesced stage: xs[t][d] = x[b2][d][t0+t]
  {
    const float* xb = x + ((size_t)(blk >> 5) * 256 + w * 64) * 2048 + (blk & 31) * 64 + lane;
    #pragma unroll 16
    for (int i = 0; i < 64; ++i)
      xs[lane][w * 64 + i] = xb[(size_t)i * 2048];
  }
  __syncthreads();

  int ord = 0;
  while (bm) {
    int row = __ffsll(bm) - 1; bm &= bm - 1;
    if ((ord++ & 3) != w) continue;
    int n = blk * 64 + row;
    int rv = __shfl(iv, row);
    int rf = rv >> 10, I = rv & 1023;
    int ka = 0, kb = 0;
    if (rf != 1023) {                      // pair: stage both candidate e rows
      int I2 = rf - 1;
      ka = min(I, I2); kb = max(I, I2);
      *(float4*)&epair[w][0][lane * 4] = *(const float4*)(e + (size_t)ka * D_DIM + lane * 4);
      *(float4*)&epair[w][1][lane * 4] = *(const float4*)(e + (size_t)kb * D_DIM + lane * 4);
    }
    asm volatile("s_waitcnt vmcnt(0) lgkmcnt(0)" ::: "memory");
    if (lane < 16) {   // exact numpy-pairwise ||x||^2: 16 chains, LDS operands
      int h = lane >> 3, jj = lane & 7;
      float a0 = xs[row][h * 128 + jj];
      float r = __fmul_rn(a0, a0);
      for (int i = 1; i < 16; ++i) {
        float a = xs[row][h * 128 + i * 8 + jj];
        r = __fadd_rn(r, __fmul_rn(a, a));
      }
      xr16[w][lane] = r;
    }
    asm volatile("s_waitcnt lgkmcnt(0)" ::: "memory");
    float xx = __fadd_rn(comb8(&xr16[w][0]), comb8(&xr16[w][8]));
    int kf;
    if (rf != 1023) {
      // pair: exact scores via LDS-operand chains, lanes 0/1
      float sv = 0.f;
      if (lane < 2) {
        const float* ep = &epair[w][lane][0];
        const float* xr = &xs[row][0];
        float a = 0.f;
        #pragma unroll 16
        for (int d = 0; d < 256; ++d) a = __fmaf_rn(xr[d], ep[d], a);
        int k = lane ? kb : ka;
        float t1 = __fadd_rn(xx, norms[k]);
        sv = t1 - 2.0f * a;
      }
      float s0 = __shfl(sv, 0), s1 = __shfl(sv, 1);
      kf = (s1 < s0) ? kb : ka;            // tie -> ka (lower)
    } else {
      // rare full exact rescan: 8 sequential chains per lane (codes ascending)
      float am[8];
      #pragma unroll
      for (int cc = 0; cc < 8; ++cc) am[cc] = 0.f;
      const float* eb = e + (size_t)(lane * 8) * D_DIM;
      for (int d4 = 0; d4 < 64; ++d4) {
        float x0 = xs[row][d4 * 4 + 0], x1 = xs[row][d4 * 4 + 1];
        float x2 = xs[row][d4 * 4 + 2], x3 = xs[row][d4 * 4 + 3];
        #pragma unroll
        for (int cc = 0; cc < 8; ++cc) {
          float4 ev = *(const float4*)(eb + (size_t)cc * D_DIM + d4 * 4);
          am[cc] = __fmaf_rn(x0, ev.x, am[cc]);
          am[cc] = __fmaf_rn(x1, ev.y, am[cc]);
          am[cc] = __fmaf_rn(x2, ev.z, am[cc]);
          am[cc] = __fmaf_rn(x3, ev.w, am[cc]);
        }
      }
      float lm = 3.4e38f; int lk = 0;
      #pragma unroll
      for (int cc = 0; cc < 8; ++cc) {
        int k = lane * 8 + cc;
        float t1 = __fadd_rn(xx, norms[k]);
        float sv = t1 - 2.0f * am[cc];
        if (sv < lm) { lm = sv; lk = k; }
      }
      #pragma unroll
      for (int off = 1; off < 64; off <<= 1) {
        float om = __shfl_xor(lm, off, 64);
        int oi = __shfl_xor(lk, off, 64);
        if (om < lm || (om == lm && oi < lk)) { lm = om; lk = oi; }
      }
      kf = lk;
    }
    if (lane == 0) out_idx[n] = (float)kf;
    float4 ev = *(const float4*)(e + (size_t)kf * D_DIM + lane * 4);
    *(float4*)(out_q + (size_t)n * D_DIM + lane * 4) = ev;
  }
}

__global__ __launch_bounds__(256) void vq_final(const double* __restrict__ bs,
                                                const double* __restrict__ bs2,
                                                float* __restrict__ out_loss) {
  __shared__ double sred[4];
  int t = threadIdx.x;
  double s = 0.0;
  for (int i = t; i < 2048; i += 256) s += bs[i];
  for (int i = t; i < 512; i += 256) s += bs2[i];
  #pragma unroll
  for (int o = 32; o > 0; o >>= 1) s += __shfl_down(s, o, 64);
  if ((t & 63) == 0) sred[t >> 6] = s;
  __syncthreads();
  if (t == 0)
    out_loss[0] = (float)(0.25 * (((sred[0] + sred[1]) + (sred[2] + sred[3])) / (double)Q_ELEMS));
}

extern "C" void kernel_launch(void* const* d_in, const int* in_sizes, int n_in,
                              void* d_out, int out_size, void* d_ws, size_t ws_size,
                              hipStream_t stream) {
  const float* x = (const float*)d_in[0];
  const float* e = (const float*)d_in[1];
  float* out = (float*)d_out;
  float* out_q = out;
  float* out_loss = out + Q_ELEMS;
  float* out_idx = out + Q_ELEMS + 1;

  char* ws = (char*)d_ws;
  float* norms = (float*)ws;
  double* bsums = (double*)(ws + 2048);
  double* bsums2 = (double*)(ws + 36864);
  unsigned short* e16 = (unsigned short*)(ws + 40960);
  unsigned short* x16 = (unsigned short*)(ws + 303104);

  vq_prep<<<K_CODES, 256, 0, stream>>>(e, norms, e16);
  vq_xpose<<<512, 512, 0, stream>>>(x, x16, bsums2);
  vq_main<<<N_ROWS / 64, 256, 0, stream>>>(norms, e16, x16, e, out_q, out_idx, bsums);
  vq_epilogue<<<N_ROWS / 64, 256, 0, stream>>>(x, e, norms, out_q, out_idx);
  vq_final<<<1, 256, 0, stream>>>(bsums, bsums2, out_loss);
}